// Round 1
// baseline (856.167 us; speedup 1.0000x reference)
//
#include <hip/hip_runtime.h>
#include <hip/hip_bf16.h>

// GCN: 4 layers, D^{-1/2}(A+I)D^{-1/2} aggregation, log_softmax output.
// Strategy: build dst-CSR once per call (atomic-free aggregation after),
// pre-scale u = dinv * (h @ W), aggregate sums via CSR gather, post-scale
// by dinv[dst], self-loop folded as +u[d]. Layer1 & layer4 transform BEFORE
// aggregation (aggregate 16 / 3 dims instead of 768 / 16).

#define DIVUP(a, b) (((a) + (b) - 1) / (b))

// ---------- edge dtype detection (int64 vs int32 ABI ambiguity) ----------
__global__ void k_detect(const void* ei, int* flag) {
    // int64 little-endian nonneg values => every odd int32 word is 0.
    int t = threadIdx.x;  // 64 threads
    const int* p = (const int*)ei;
    bool z = (p[2 * t + 1] == 0);
    unsigned long long m = __ballot(z);
    if (t == 0) *flag = (m == ~0ULL) ? 1 : 0;
}

__device__ __forceinline__ int load_idx(const void* ei, int is64, size_t pos) {
    if (is64) return (int)((const long long*)ei)[pos];
    return ((const int*)ei)[pos];
}

// ---------- degree count ----------
__global__ void k_init(int* cnt, int n) {
    int i = blockIdx.x * 256 + threadIdx.x;
    if (i < n) cnt[i] = 0;
}

__global__ void k_count(const void* ei, const int* flag, int* cnt, int E) {
    int e = blockIdx.x * 256 + threadIdx.x;
    if (e >= E) return;
    int is64 = *flag;
    int d = load_idx(ei, is64, (size_t)E + e);
    atomicAdd(&cnt[d], 1);
}

// ---------- exclusive scan (3-phase) ----------
__global__ void k_scanA(const int* cnt, int* offs, int* bsums, int n) {
    __shared__ int s[256];
    int t = threadIdx.x;
    int i = blockIdx.x * 256 + t;
    int v = (i < n) ? cnt[i] : 0;
    s[t] = v;
    __syncthreads();
    for (int off = 1; off < 256; off <<= 1) {
        int add = (t >= off) ? s[t - off] : 0;
        __syncthreads();
        s[t] += add;
        __syncthreads();
    }
    if (i < n) offs[i] = s[t] - v;          // block-local exclusive
    if (t == 255) bsums[blockIdx.x] = s[t]; // block total
}

__global__ void k_scanB(int* bsums, int nb) {
    __shared__ int s[512];
    int t = threadIdx.x;
    int v = (t < nb) ? bsums[t] : 0;
    s[t] = v;
    __syncthreads();
    for (int off = 1; off < 512; off <<= 1) {
        int add = (t >= off) ? s[t - off] : 0;
        __syncthreads();
        s[t] += add;
        __syncthreads();
    }
    if (t < nb) bsums[t] = s[t] - v;        // exclusive over block sums
}

__global__ void k_scanC(int* offs, int* cursor, const int* bsums,
                        const int* cnt, float* dinv, int n) {
    int i = blockIdx.x * 256 + threadIdx.x;
    if (i >= n) return;
    int o = offs[i] + bsums[blockIdx.x];
    offs[i] = o;
    cursor[i] = o;
    dinv[i] = rsqrtf((float)(cnt[i] + 1));  // +1 self-loop
}

// ---------- CSR fill ----------
__global__ void k_fill(const void* ei, const int* flag, int* cursor, int* col, int E) {
    int e = blockIdx.x * 256 + threadIdx.x;
    if (e >= E) return;
    int is64 = *flag;
    int s = load_idx(ei, is64, (size_t)e);
    int d = load_idx(ei, is64, (size_t)E + e);
    int p = atomicAdd(&cursor[d], 1);
    col[p] = s;
}

// ---------- transform: u = dinv * (in @ W),  W is (IND,16) row-major ----------
__device__ __forceinline__ void fma4(float s, const float4 w, float4& a) {
    a.x = fmaf(s, w.x, a.x);
    a.y = fmaf(s, w.y, a.y);
    a.z = fmaf(s, w.z, a.z);
    a.w = fmaf(s, w.w, a.w);
}

template <int IND>
__global__ void k_transform(const float* __restrict__ in, const float* __restrict__ W,
                            const float* __restrict__ dinv, float* __restrict__ out, int n) {
    int gid = blockIdx.x * 256 + threadIdx.x;
    int node = gid >> 2, og = gid & 3;  // 4 threads per node, 4 out-dims each
    if (node >= n) return;
    const float4* xr = (const float4*)(in + (size_t)node * IND);
    const float4* w4 = (const float4*)W;  // row k = float4s [k*4 .. k*4+3]
    float4 acc = {0.f, 0.f, 0.f, 0.f};
    for (int kk = 0; kk < IND / 4; ++kk) {
        float4 xv = xr[kk];
        int k4 = kk * 16;  // float4 index of W row 4*kk
        fma4(xv.x, w4[k4 + og], acc);
        fma4(xv.y, w4[k4 + 4 + og], acc);
        fma4(xv.z, w4[k4 + 8 + og], acc);
        fma4(xv.w, w4[k4 + 12 + og], acc);
    }
    float s = dinv[node];
    float4 r = {acc.x * s, acc.y * s, acc.z * s, acc.w * s};
    ((float4*)out)[(size_t)node * 4 + og] = r;
}

// ---------- transform layer 4: u4 = dinv * (h @ W4), W4 is (16,3), pad to float4 ----------
__global__ void k_t4(const float* __restrict__ h, const float* __restrict__ W4,
                     const float* __restrict__ dinv, float4* __restrict__ u4p, int n) {
    int node = blockIdx.x * 256 + threadIdx.x;
    if (node >= n) return;
    const float* hr = h + (size_t)node * 16;
    float a0 = 0.f, a1 = 0.f, a2 = 0.f;
#pragma unroll
    for (int k = 0; k < 16; ++k) {
        float hk = hr[k];
        a0 = fmaf(hk, W4[k * 3 + 0], a0);
        a1 = fmaf(hk, W4[k * 3 + 1], a1);
        a2 = fmaf(hk, W4[k * 3 + 2], a2);
    }
    float s = dinv[node];
    u4p[node] = make_float4(a0 * s, a1 * s, a2 * s, 0.f);
}

// ---------- aggregate 16-dim: h[d] = relu(dinv[d]*(sum_{src} u[src] + u[d]) + b) ----------
__global__ void k_agg16(const float* __restrict__ u, const int* __restrict__ col,
                        const int* __restrict__ offs, const int* __restrict__ cnt,
                        const float* __restrict__ dinv, const float* __restrict__ b,
                        float* __restrict__ hout, int n) {
    int wave = threadIdx.x >> 6;
    int node = blockIdx.x * 4 + wave;  // one wave per node
    if (node >= n) return;
    int lane = threadIdx.x & 63;
    int eslot = lane >> 2, comp = lane & 3;  // 16 edges in flight, float4 per lane
    const float4* u4 = (const float4*)u;
    int beg = offs[node], c = cnt[node];
    float4 acc = {0.f, 0.f, 0.f, 0.f};
    for (int i = eslot; i < c; i += 16) {
        int s = col[beg + i];
        float4 v = u4[(size_t)s * 4 + comp];
        acc.x += v.x; acc.y += v.y; acc.z += v.z; acc.w += v.w;
    }
    // reduce across the 16 edge-slots (keep comp lanes separate)
    for (int off = 4; off < 64; off <<= 1) {
        acc.x += __shfl_xor(acc.x, off, 64);
        acc.y += __shfl_xor(acc.y, off, 64);
        acc.z += __shfl_xor(acc.z, off, 64);
        acc.w += __shfl_xor(acc.w, off, 64);
    }
    if (eslot == 0) {  // lanes 0..3 hold comp 0..3
        float4 self = u4[(size_t)node * 4 + comp];
        float dv = dinv[node];
        float4 bb = ((const float4*)b)[comp];
        float4 r;
        r.x = fmaxf(fmaf(dv, acc.x + self.x, bb.x), 0.f);
        r.y = fmaxf(fmaf(dv, acc.y + self.y, bb.y), 0.f);
        r.z = fmaxf(fmaf(dv, acc.z + self.z, bb.z), 0.f);
        r.w = fmaxf(fmaf(dv, acc.w + self.w, bb.w), 0.f);
        ((float4*)hout)[(size_t)node * 4 + comp] = r;
    }
}

// ---------- final aggregate (3 dims) + bias + log_softmax ----------
__global__ void k_agg_out(const float4* __restrict__ u4p, const int* __restrict__ col,
                          const int* __restrict__ offs, const int* __restrict__ cnt,
                          const float* __restrict__ dinv, const float* __restrict__ b4,
                          float* __restrict__ out, int n) {
    int wave = threadIdx.x >> 6;
    int node = blockIdx.x * 4 + wave;
    if (node >= n) return;
    int lane = threadIdx.x & 63;
    int beg = offs[node], c = cnt[node];
    float a0 = 0.f, a1 = 0.f, a2 = 0.f;
    for (int i = lane; i < c; i += 64) {
        float4 v = u4p[col[beg + i]];
        a0 += v.x; a1 += v.y; a2 += v.z;
    }
    for (int off = 1; off < 64; off <<= 1) {
        a0 += __shfl_xor(a0, off, 64);
        a1 += __shfl_xor(a1, off, 64);
        a2 += __shfl_xor(a2, off, 64);
    }
    if (lane == 0) {
        float4 self = u4p[node];
        float dv = dinv[node];
        float v0 = fmaf(dv, a0 + self.x, b4[0]);
        float v1 = fmaf(dv, a1 + self.y, b4[1]);
        float v2 = fmaf(dv, a2 + self.z, b4[2]);
        float m = fmaxf(v0, fmaxf(v1, v2));
        float lse = m + logf(expf(v0 - m) + expf(v1 - m) + expf(v2 - m));
        out[(size_t)node * 3 + 0] = v0 - lse;
        out[(size_t)node * 3 + 1] = v1 - lse;
        out[(size_t)node * 3 + 2] = v2 - lse;
    }
}

extern "C" void kernel_launch(void* const* d_in, const int* in_sizes, int n_in,
                              void* d_out, int out_size, void* d_ws, size_t ws_size,
                              hipStream_t stream) {
    const float* x  = (const float*)d_in[0];
    const void*  ei = d_in[1];
    const float* W1 = (const float*)d_in[2];
    const float* b1 = (const float*)d_in[3];
    const float* W2 = (const float*)d_in[4];
    const float* b2 = (const float*)d_in[5];
    const float* W3 = (const float*)d_in[6];
    const float* b3 = (const float*)d_in[7];
    const float* W4 = (const float*)d_in[8];
    const float* b4 = (const float*)d_in[9];
    float* out = (float*)d_out;

    const int N = in_sizes[0] / 768;
    const int E = in_sizes[1] / 2;

    // workspace carve (256B aligned)
    char* p = (char*)d_ws;
    auto alloc = [&](size_t bytes) {
        void* r = (void*)p;
        p += (bytes + 255) & ~(size_t)255;
        return r;
    };
    int*   cnt    = (int*)alloc((size_t)N * 4);
    int*   offs   = (int*)alloc((size_t)N * 4);
    int*   cursor = (int*)alloc((size_t)N * 4);
    int*   bsums  = (int*)alloc(4096);
    int*   flag   = (int*)alloc(256);
    float* dinv   = (float*)alloc((size_t)N * 4);
    int*   col    = (int*)alloc((size_t)E * 4);
    float* u      = (float*)alloc((size_t)N * 16 * 4);
    float* h      = (float*)alloc((size_t)N * 16 * 4);
    float4* u4p   = (float4*)alloc((size_t)N * 16);

    const int nbN = DIVUP(N, 256);
    const int nbE = DIVUP(E, 256);
    const int nbT = DIVUP(4 * N, 256);
    const int nbA = DIVUP(N, 4);

    k_detect<<<1, 64, 0, stream>>>(ei, flag);
    k_init<<<nbN, 256, 0, stream>>>(cnt, N);
    k_count<<<nbE, 256, 0, stream>>>(ei, flag, cnt, E);
    k_scanA<<<nbN, 256, 0, stream>>>(cnt, offs, bsums, N);
    k_scanB<<<1, 512, 0, stream>>>(bsums, nbN);
    k_scanC<<<nbN, 256, 0, stream>>>(offs, cursor, bsums, cnt, dinv, N);
    k_fill<<<nbE, 256, 0, stream>>>(ei, flag, cursor, col, E);

    // layer 1: transform(768->16) then aggregate
    k_transform<768><<<nbT, 256, 0, stream>>>(x, W1, dinv, u, N);
    k_agg16<<<nbA, 256, 0, stream>>>(u, col, offs, cnt, dinv, b1, h, N);
    // layer 2
    k_transform<16><<<nbT, 256, 0, stream>>>(h, W2, dinv, u, N);
    k_agg16<<<nbA, 256, 0, stream>>>(u, col, offs, cnt, dinv, b2, h, N);
    // layer 3
    k_transform<16><<<nbT, 256, 0, stream>>>(h, W3, dinv, u, N);
    k_agg16<<<nbA, 256, 0, stream>>>(u, col, offs, cnt, dinv, b3, h, N);
    // layer 4: transform(16->3) then aggregate + log_softmax
    k_t4<<<nbN, 256, 0, stream>>>(h, W4, dinv, u4p, N);
    k_agg_out<<<nbA, 256, 0, stream>>>(u4p, col, offs, cnt, dinv, b4, out, N);
}

// Round 2
// 792.851 us; speedup vs baseline: 1.0799x; 1.0799x over previous
//
#include <hip/hip_runtime.h>
#include <hip/hip_bf16.h>

// GCN: 4 layers, D^{-1/2}(A+I)D^{-1/2} aggregation, log_softmax output.
// CSR built per call (atomic-free aggregation after); u = dinv*(h@W) pre-scale,
// CSR gather sums, post-scale by dinv[dst], self-loop folded as +u[d].
// Layer1/4 transform BEFORE aggregation (aggregate 16/3 dims, not 768/16).
// R1: k_fill/k_count were latency-bound (VALUBusy 0.4%, 1 edge/thread) ->
// 4 edges/thread with batched independent loads/atomics/stores.

#define DIVUP(a, b) (((a) + (b) - 1) / (b))

// ---------- edge dtype detection (int64 vs int32 ABI ambiguity) ----------
__global__ void k_detect(const void* ei, int* flag) {
    // int64 little-endian nonneg values => every odd int32 word is 0.
    int t = threadIdx.x;  // 64 threads
    const int* p = (const int*)ei;
    bool z = (p[2 * t + 1] == 0);
    unsigned long long m = __ballot(z);
    if (t == 0) *flag = (m == ~0ULL) ? 1 : 0;
}

__device__ __forceinline__ int load_idx(const void* ei, int is64, size_t pos) {
    if (is64) return (int)((const long long*)ei)[pos];
    return ((const int*)ei)[pos];
}

// ---------- degree count ----------
__global__ void k_init(int* cnt, int n) {
    int i = blockIdx.x * 256 + threadIdx.x;
    if (i < n) cnt[i] = 0;
}

// 4 edges/thread, block-strided so each load instruction stays coalesced.
__global__ void k_count(const void* ei, const int* flag, int* cnt, int E) {
    int base = blockIdx.x * 1024 + threadIdx.x;
    int is64 = *flag;
    int d[4];
    bool ok[4];
#pragma unroll
    for (int j = 0; j < 4; ++j) {
        int e = base + j * 256;
        ok[j] = (e < E);
        d[j] = ok[j] ? load_idx(ei, is64, (size_t)E + e) : 0;
    }
#pragma unroll
    for (int j = 0; j < 4; ++j)
        if (ok[j]) atomicAdd(&cnt[d[j]], 1);
}

// ---------- exclusive scan (3-phase) ----------
__global__ void k_scanA(const int* cnt, int* offs, int* bsums, int n) {
    __shared__ int s[256];
    int t = threadIdx.x;
    int i = blockIdx.x * 256 + t;
    int v = (i < n) ? cnt[i] : 0;
    s[t] = v;
    __syncthreads();
    for (int off = 1; off < 256; off <<= 1) {
        int add = (t >= off) ? s[t - off] : 0;
        __syncthreads();
        s[t] += add;
        __syncthreads();
    }
    if (i < n) offs[i] = s[t] - v;          // block-local exclusive
    if (t == 255) bsums[blockIdx.x] = s[t]; // block total
}

__global__ void k_scanB(int* bsums, int nb) {
    __shared__ int s[512];
    int t = threadIdx.x;
    int v = (t < nb) ? bsums[t] : 0;
    s[t] = v;
    __syncthreads();
    for (int off = 1; off < 512; off <<= 1) {
        int add = (t >= off) ? s[t - off] : 0;
        __syncthreads();
        s[t] += add;
        __syncthreads();
    }
    if (t < nb) bsums[t] = s[t] - v;        // exclusive over block sums
}

__global__ void k_scanC(int* offs, int* cursor, const int* bsums,
                        const int* cnt, float* dinv, int n) {
    int i = blockIdx.x * 256 + threadIdx.x;
    if (i >= n) return;
    int o = offs[i] + bsums[blockIdx.x];
    offs[i] = o;
    cursor[i] = o;
    dinv[i] = rsqrtf((float)(cnt[i] + 1));  // +1 self-loop
}

// ---------- CSR fill: 4 edges/thread, batched loads -> atomics -> stores ----------
__global__ void k_fill(const void* ei, const int* flag, int* cursor, int* col, int E) {
    int base = blockIdx.x * 1024 + threadIdx.x;
    int is64 = *flag;
    int s[4], d[4], p[4];
    bool ok[4];
#pragma unroll
    for (int j = 0; j < 4; ++j) {
        int e = base + j * 256;
        ok[j] = (e < E);
        s[j] = ok[j] ? load_idx(ei, is64, (size_t)e) : 0;
        d[j] = ok[j] ? load_idx(ei, is64, (size_t)E + e) : 0;
    }
#pragma unroll
    for (int j = 0; j < 4; ++j)
        p[j] = ok[j] ? atomicAdd(&cursor[d[j]], 1) : 0;
#pragma unroll
    for (int j = 0; j < 4; ++j)
        if (ok[j]) col[p[j]] = s[j];
}

// ---------- transform: u = dinv * (in @ W),  W is (IND,16) row-major ----------
__device__ __forceinline__ void fma4(float s, const float4 w, float4& a) {
    a.x = fmaf(s, w.x, a.x);
    a.y = fmaf(s, w.y, a.y);
    a.z = fmaf(s, w.z, a.z);
    a.w = fmaf(s, w.w, a.w);
}

template <int IND>
__global__ void k_transform(const float* __restrict__ in, const float* __restrict__ W,
                            const float* __restrict__ dinv, float* __restrict__ out, int n) {
    int gid = blockIdx.x * 256 + threadIdx.x;
    int node = gid >> 2, og = gid & 3;  // 4 threads per node, 4 out-dims each
    if (node >= n) return;
    const float4* xr = (const float4*)(in + (size_t)node * IND);
    const float4* w4 = (const float4*)W;  // row k = float4s [k*4 .. k*4+3]
    float4 acc = {0.f, 0.f, 0.f, 0.f};
    for (int kk = 0; kk < IND / 4; ++kk) {
        float4 xv = xr[kk];
        int k4 = kk * 16;  // float4 index of W row 4*kk
        fma4(xv.x, w4[k4 + og], acc);
        fma4(xv.y, w4[k4 + 4 + og], acc);
        fma4(xv.z, w4[k4 + 8 + og], acc);
        fma4(xv.w, w4[k4 + 12 + og], acc);
    }
    float s = dinv[node];
    float4 r = {acc.x * s, acc.y * s, acc.z * s, acc.w * s};
    ((float4*)out)[(size_t)node * 4 + og] = r;
}

// ---------- transform layer 4: u4 = dinv * (h @ W4), W4 is (16,3), pad to float4 ----------
__global__ void k_t4(const float* __restrict__ h, const float* __restrict__ W4,
                     const float* __restrict__ dinv, float4* __restrict__ u4p, int n) {
    int node = blockIdx.x * 256 + threadIdx.x;
    if (node >= n) return;
    const float* hr = h + (size_t)node * 16;
    float a0 = 0.f, a1 = 0.f, a2 = 0.f;
#pragma unroll
    for (int k = 0; k < 16; ++k) {
        float hk = hr[k];
        a0 = fmaf(hk, W4[k * 3 + 0], a0);
        a1 = fmaf(hk, W4[k * 3 + 1], a1);
        a2 = fmaf(hk, W4[k * 3 + 2], a2);
    }
    float s = dinv[node];
    u4p[node] = make_float4(a0 * s, a1 * s, a2 * s, 0.f);
}

// ---------- aggregate 16-dim: h[d] = relu(dinv[d]*(sum_{src} u[src] + u[d]) + b) ----------
__global__ void k_agg16(const float* __restrict__ u, const int* __restrict__ col,
                        const int* __restrict__ offs, const int* __restrict__ cnt,
                        const float* __restrict__ dinv, const float* __restrict__ b,
                        float* __restrict__ hout, int n) {
    int wave = threadIdx.x >> 6;
    int node = blockIdx.x * 4 + wave;  // one wave per node
    if (node >= n) return;
    int lane = threadIdx.x & 63;
    int eslot = lane >> 2, comp = lane & 3;  // 16 edges in flight, float4 per lane
    const float4* u4 = (const float4*)u;
    int beg = offs[node], c = cnt[node];
    float4 acc = {0.f, 0.f, 0.f, 0.f};
    float4 acc2 = {0.f, 0.f, 0.f, 0.f};
    int i = eslot;
    for (; i + 16 < c; i += 32) {  // two independent gathers in flight
        int s0 = col[beg + i];
        int s1 = col[beg + i + 16];
        float4 v0 = u4[(size_t)s0 * 4 + comp];
        float4 v1 = u4[(size_t)s1 * 4 + comp];
        acc.x += v0.x; acc.y += v0.y; acc.z += v0.z; acc.w += v0.w;
        acc2.x += v1.x; acc2.y += v1.y; acc2.z += v1.z; acc2.w += v1.w;
    }
    if (i < c) {
        int s0 = col[beg + i];
        float4 v0 = u4[(size_t)s0 * 4 + comp];
        acc.x += v0.x; acc.y += v0.y; acc.z += v0.z; acc.w += v0.w;
    }
    acc.x += acc2.x; acc.y += acc2.y; acc.z += acc2.z; acc.w += acc2.w;
    // reduce across the 16 edge-slots (keep comp lanes separate)
    for (int off = 4; off < 64; off <<= 1) {
        acc.x += __shfl_xor(acc.x, off, 64);
        acc.y += __shfl_xor(acc.y, off, 64);
        acc.z += __shfl_xor(acc.z, off, 64);
        acc.w += __shfl_xor(acc.w, off, 64);
    }
    if (eslot == 0) {  // lanes 0..3 hold comp 0..3
        float4 self = u4[(size_t)node * 4 + comp];
        float dv = dinv[node];
        float4 bb = ((const float4*)b)[comp];
        float4 r;
        r.x = fmaxf(fmaf(dv, acc.x + self.x, bb.x), 0.f);
        r.y = fmaxf(fmaf(dv, acc.y + self.y, bb.y), 0.f);
        r.z = fmaxf(fmaf(dv, acc.z + self.z, bb.z), 0.f);
        r.w = fmaxf(fmaf(dv, acc.w + self.w, bb.w), 0.f);
        ((float4*)hout)[(size_t)node * 4 + comp] = r;
    }
}

// ---------- final aggregate (3 dims) + bias + log_softmax ----------
__global__ void k_agg_out(const float4* __restrict__ u4p, const int* __restrict__ col,
                          const int* __restrict__ offs, const int* __restrict__ cnt,
                          const float* __restrict__ dinv, const float* __restrict__ b4,
                          float* __restrict__ out, int n) {
    int wave = threadIdx.x >> 6;
    int node = blockIdx.x * 4 + wave;
    if (node >= n) return;
    int lane = threadIdx.x & 63;
    int beg = offs[node], c = cnt[node];
    float a0 = 0.f, a1 = 0.f, a2 = 0.f;
    for (int i = lane; i < c; i += 64) {
        float4 v = u4p[col[beg + i]];
        a0 += v.x; a1 += v.y; a2 += v.z;
    }
    for (int off = 1; off < 64; off <<= 1) {
        a0 += __shfl_xor(a0, off, 64);
        a1 += __shfl_xor(a1, off, 64);
        a2 += __shfl_xor(a2, off, 64);
    }
    if (lane == 0) {
        float4 self = u4p[node];
        float dv = dinv[node];
        float v0 = fmaf(dv, a0 + self.x, b4[0]);
        float v1 = fmaf(dv, a1 + self.y, b4[1]);
        float v2 = fmaf(dv, a2 + self.z, b4[2]);
        float m = fmaxf(v0, fmaxf(v1, v2));
        float lse = m + logf(expf(v0 - m) + expf(v1 - m) + expf(v2 - m));
        out[(size_t)node * 3 + 0] = v0 - lse;
        out[(size_t)node * 3 + 1] = v1 - lse;
        out[(size_t)node * 3 + 2] = v2 - lse;
    }
}

extern "C" void kernel_launch(void* const* d_in, const int* in_sizes, int n_in,
                              void* d_out, int out_size, void* d_ws, size_t ws_size,
                              hipStream_t stream) {
    const float* x  = (const float*)d_in[0];
    const void*  ei = d_in[1];
    const float* W1 = (const float*)d_in[2];
    const float* b1 = (const float*)d_in[3];
    const float* W2 = (const float*)d_in[4];
    const float* b2 = (const float*)d_in[5];
    const float* W3 = (const float*)d_in[6];
    const float* b3 = (const float*)d_in[7];
    const float* W4 = (const float*)d_in[8];
    const float* b4 = (const float*)d_in[9];
    float* out = (float*)d_out;

    const int N = in_sizes[0] / 768;
    const int E = in_sizes[1] / 2;

    // workspace carve (256B aligned)
    char* p = (char*)d_ws;
    auto alloc = [&](size_t bytes) {
        void* r = (void*)p;
        p += (bytes + 255) & ~(size_t)255;
        return r;
    };
    int*   cnt    = (int*)alloc((size_t)N * 4);
    int*   offs   = (int*)alloc((size_t)N * 4);
    int*   cursor = (int*)alloc((size_t)N * 4);
    int*   bsums  = (int*)alloc(4096);
    int*   flag   = (int*)alloc(256);
    float* dinv   = (float*)alloc((size_t)N * 4);
    int*   col    = (int*)alloc((size_t)E * 4);
    float* u      = (float*)alloc((size_t)N * 16 * 4);
    float* h      = (float*)alloc((size_t)N * 16 * 4);
    float4* u4p   = (float4*)alloc((size_t)N * 16);

    const int nbN = DIVUP(N, 256);
    const int nbE4 = DIVUP(E, 1024);  // 4 edges/thread
    const int nbT = DIVUP(4 * N, 256);
    const int nbA = DIVUP(N, 4);

    k_detect<<<1, 64, 0, stream>>>(ei, flag);
    k_init<<<nbN, 256, 0, stream>>>(cnt, N);
    k_count<<<nbE4, 256, 0, stream>>>(ei, flag, cnt, E);
    k_scanA<<<nbN, 256, 0, stream>>>(cnt, offs, bsums, N);
    k_scanB<<<1, 512, 0, stream>>>(bsums, nbN);
    k_scanC<<<nbN, 256, 0, stream>>>(offs, cursor, bsums, cnt, dinv, N);
    k_fill<<<nbE4, 256, 0, stream>>>(ei, flag, cursor, col, E);

    // layer 1: transform(768->16) then aggregate
    k_transform<768><<<nbT, 256, 0, stream>>>(x, W1, dinv, u, N);
    k_agg16<<<nbA, 256, 0, stream>>>(u, col, offs, cnt, dinv, b1, h, N);
    // layer 2
    k_transform<16><<<nbT, 256, 0, stream>>>(h, W2, dinv, u, N);
    k_agg16<<<nbA, 256, 0, stream>>>(u, col, offs, cnt, dinv, b2, h, N);
    // layer 3
    k_transform<16><<<nbT, 256, 0, stream>>>(h, W3, dinv, u, N);
    k_agg16<<<nbA, 256, 0, stream>>>(u, col, offs, cnt, dinv, b3, h, N);
    // layer 4: transform(16->3) then aggregate + log_softmax
    k_t4<<<nbN, 256, 0, stream>>>(h, W4, dinv, u4p, N);
    k_agg_out<<<nbA, 256, 0, stream>>>(u4p, col, offs, cnt, dinv, b4, out, N);
}

// Round 3
// 739.746 us; speedup vs baseline: 1.1574x; 1.0718x over previous
//
#include <hip/hip_runtime.h>
#include <hip/hip_bf16.h>

// GCN: 4 layers, D^{-1/2}(A+I)D^{-1/2} aggregation, log_softmax output.
// CSR built per call (atomic-free aggregation after); u = dinv*(h@W) pre-scale,
// CSR gather sums, post-scale by dinv[dst], self-loop folded as +u[d].
// Layer1/4 transform BEFORE aggregation (aggregate 16/3 dims, not 768/16).
// R1: k_fill/k_count latency-bound -> batched edges/thread.
// R2: k_transform<768> was 25%-load-efficiency (quad-broadcast reads, 281us)
//     -> wave-private LDS tile staging, coalesced 1KB/wave loads, no barrier.

#define DIVUP(a, b) (((a) + (b) - 1) / (b))

// ---------- edge dtype detection (int64 vs int32 ABI ambiguity) ----------
__global__ void k_detect(const void* ei, int* flag) {
    int t = threadIdx.x;  // 64 threads
    const int* p = (const int*)ei;
    bool z = (p[2 * t + 1] == 0);
    unsigned long long m = __ballot(z);
    if (t == 0) *flag = (m == ~0ULL) ? 1 : 0;
}

__device__ __forceinline__ int load_idx(const void* ei, int is64, size_t pos) {
    if (is64) return (int)((const long long*)ei)[pos];
    return ((const int*)ei)[pos];
}

// ---------- degree count ----------
__global__ void k_init(int* cnt, int n) {
    int i = blockIdx.x * 256 + threadIdx.x;
    if (i < n) cnt[i] = 0;
}

// 8 edges/thread, block-strided coalesced loads, batched atomics.
__global__ void k_count(const void* ei, const int* flag, int* cnt, int E) {
    int base = blockIdx.x * 2048 + threadIdx.x;
    int is64 = *flag;
    int d[8];
    bool ok[8];
#pragma unroll
    for (int j = 0; j < 8; ++j) {
        int e = base + j * 256;
        ok[j] = (e < E);
        d[j] = ok[j] ? load_idx(ei, is64, (size_t)E + e) : 0;
    }
#pragma unroll
    for (int j = 0; j < 8; ++j)
        if (ok[j]) atomicAdd(&cnt[d[j]], 1);
}

// ---------- exclusive scan (3-phase) ----------
__global__ void k_scanA(const int* cnt, int* offs, int* bsums, int n) {
    __shared__ int s[256];
    int t = threadIdx.x;
    int i = blockIdx.x * 256 + t;
    int v = (i < n) ? cnt[i] : 0;
    s[t] = v;
    __syncthreads();
    for (int off = 1; off < 256; off <<= 1) {
        int add = (t >= off) ? s[t - off] : 0;
        __syncthreads();
        s[t] += add;
        __syncthreads();
    }
    if (i < n) offs[i] = s[t] - v;
    if (t == 255) bsums[blockIdx.x] = s[t];
}

__global__ void k_scanB(int* bsums, int nb) {
    __shared__ int s[512];
    int t = threadIdx.x;
    int v = (t < nb) ? bsums[t] : 0;
    s[t] = v;
    __syncthreads();
    for (int off = 1; off < 512; off <<= 1) {
        int add = (t >= off) ? s[t - off] : 0;
        __syncthreads();
        s[t] += add;
        __syncthreads();
    }
    if (t < nb) bsums[t] = s[t] - v;
}

__global__ void k_scanC(int* offs, int* cursor, const int* bsums,
                        const int* cnt, float* dinv, int n) {
    int i = blockIdx.x * 256 + threadIdx.x;
    if (i >= n) return;
    int o = offs[i] + bsums[blockIdx.x];
    offs[i] = o;
    cursor[i] = o;
    dinv[i] = rsqrtf((float)(cnt[i] + 1));  // +1 self-loop
}

// ---------- CSR fill: 8 edges/thread ----------
__global__ void k_fill(const void* ei, const int* flag, int* cursor, int* col, int E) {
    int base = blockIdx.x * 2048 + threadIdx.x;
    int is64 = *flag;
    int s[8], d[8], p[8];
    bool ok[8];
#pragma unroll
    for (int j = 0; j < 8; ++j) {
        int e = base + j * 256;
        ok[j] = (e < E);
        s[j] = ok[j] ? load_idx(ei, is64, (size_t)e) : 0;
        d[j] = ok[j] ? load_idx(ei, is64, (size_t)E + e) : 0;
    }
#pragma unroll
    for (int j = 0; j < 8; ++j)
        p[j] = ok[j] ? atomicAdd(&cursor[d[j]], 1) : 0;
#pragma unroll
    for (int j = 0; j < 8; ++j)
        if (ok[j]) col[p[j]] = s[j];
}

__device__ __forceinline__ void fma4(float s, const float4 w, float4& a) {
    a.x = fmaf(s, w.x, a.x);
    a.y = fmaf(s, w.y, a.y);
    a.z = fmaf(s, w.z, a.z);
    a.w = fmaf(s, w.w, a.w);
}

// ---------- layer-1 transform: u = dinv * (x @ W1), coalesced via LDS tiles ----------
// Block = 256 threads = 4 waves; each wave owns 16 nodes (wave-private LDS
// slice -> no __syncthreads). 12 tiles of 64 cols: stage 16x64 floats
// (padded stride 68 -> 2-way bank alias = free), quads compute from LDS.
__global__ void k_transform768(const float* __restrict__ x, const float* __restrict__ W,
                               const float* __restrict__ dinv, float* __restrict__ out, int n) {
    __shared__ float lx[4][16][68];
    int tid = threadIdx.x;
    int wid = tid >> 6, lane = tid & 63;
    int nbase = blockIdx.x * 64 + wid * 16;
    int nloc = lane >> 2, og = lane & 3;
    int node = nbase + nloc;
    const float4* xg = (const float4*)x;
    const float4* w4 = (const float4*)W;  // W row k = float4s [k*4 .. k*4+3]
    float4 acc = {0.f, 0.f, 0.f, 0.f};
    const float* lxr = lx[wid][nloc];
#pragma unroll 1
    for (int t = 0; t < 12; ++t) {
        // stage: 16 rows x 16 float4, coalesced (lane-consecutive cols)
#pragma unroll
        for (int r = 0; r < 4; ++r) {
            int f = r * 64 + lane;
            int srow = f >> 4, scol = f & 15;
            int nb = nbase + srow;
            if (nb < n) {
                float4 v = xg[(size_t)nb * 192 + t * 16 + scol];
                *(float4*)&lx[wid][srow][scol * 4] = v;
            }
        }
        // compute from LDS (quad-broadcast reads, free)
#pragma unroll 4
        for (int kk = 0; kk < 16; ++kk) {
            float4 xv = *(const float4*)&lxr[kk * 4];
            int k = t * 64 + kk * 4;
            fma4(xv.x, w4[(k + 0) * 4 + og], acc);
            fma4(xv.y, w4[(k + 1) * 4 + og], acc);
            fma4(xv.z, w4[(k + 2) * 4 + og], acc);
            fma4(xv.w, w4[(k + 3) * 4 + og], acc);
        }
    }
    if (node < n) {
        float s = dinv[node];
        float4 r = {acc.x * s, acc.y * s, acc.z * s, acc.w * s};
        ((float4*)out)[(size_t)node * 4 + og] = r;
    }
}

// ---------- 16->16 transform: u = dinv * (h @ W) ----------
__global__ void k_transform16(const float* __restrict__ in, const float* __restrict__ W,
                              const float* __restrict__ dinv, float* __restrict__ out, int n) {
    int gid = blockIdx.x * 256 + threadIdx.x;
    int node = gid >> 2, og = gid & 3;
    if (node >= n) return;
    const float4* xr = (const float4*)(in + (size_t)node * 16);
    const float4* w4 = (const float4*)W;
    float4 acc = {0.f, 0.f, 0.f, 0.f};
#pragma unroll
    for (int kk = 0; kk < 4; ++kk) {
        float4 xv = xr[kk];
        int k4 = kk * 16;
        fma4(xv.x, w4[k4 + og], acc);
        fma4(xv.y, w4[k4 + 4 + og], acc);
        fma4(xv.z, w4[k4 + 8 + og], acc);
        fma4(xv.w, w4[k4 + 12 + og], acc);
    }
    float s = dinv[node];
    float4 r = {acc.x * s, acc.y * s, acc.z * s, acc.w * s};
    ((float4*)out)[(size_t)node * 4 + og] = r;
}

// ---------- layer-4 transform: u4 = dinv * (h @ W4), W4 (16,3) padded to float4 ----------
__global__ void k_t4(const float* __restrict__ h, const float* __restrict__ W4,
                     const float* __restrict__ dinv, float4* __restrict__ u4p, int n) {
    int node = blockIdx.x * 256 + threadIdx.x;
    if (node >= n) return;
    const float* hr = h + (size_t)node * 16;
    float a0 = 0.f, a1 = 0.f, a2 = 0.f;
#pragma unroll
    for (int k = 0; k < 16; ++k) {
        float hk = hr[k];
        a0 = fmaf(hk, W4[k * 3 + 0], a0);
        a1 = fmaf(hk, W4[k * 3 + 1], a1);
        a2 = fmaf(hk, W4[k * 3 + 2], a2);
    }
    float s = dinv[node];
    u4p[node] = make_float4(a0 * s, a1 * s, a2 * s, 0.f);
}

// ---------- aggregate 16-dim: h[d] = relu(dinv[d]*(sum_{src} u[src] + u[d]) + b) ----------
__global__ void k_agg16(const float* __restrict__ u, const int* __restrict__ col,
                        const int* __restrict__ offs, const int* __restrict__ cnt,
                        const float* __restrict__ dinv, const float* __restrict__ b,
                        float* __restrict__ hout, int n) {
    int wave = threadIdx.x >> 6;
    int node = blockIdx.x * 4 + wave;  // one wave per node
    if (node >= n) return;
    int lane = threadIdx.x & 63;
    int eslot = lane >> 2, comp = lane & 3;
    const float4* u4 = (const float4*)u;
    int beg = offs[node], c = cnt[node];
    float4 acc = {0.f, 0.f, 0.f, 0.f};
    float4 acc2 = {0.f, 0.f, 0.f, 0.f};
    int i = eslot;
    for (; i + 16 < c; i += 32) {
        int s0 = col[beg + i];
        int s1 = col[beg + i + 16];
        float4 v0 = u4[(size_t)s0 * 4 + comp];
        float4 v1 = u4[(size_t)s1 * 4 + comp];
        acc.x += v0.x; acc.y += v0.y; acc.z += v0.z; acc.w += v0.w;
        acc2.x += v1.x; acc2.y += v1.y; acc2.z += v1.z; acc2.w += v1.w;
    }
    if (i < c) {
        int s0 = col[beg + i];
        float4 v0 = u4[(size_t)s0 * 4 + comp];
        acc.x += v0.x; acc.y += v0.y; acc.z += v0.z; acc.w += v0.w;
    }
    acc.x += acc2.x; acc.y += acc2.y; acc.z += acc2.z; acc.w += acc2.w;
    for (int off = 4; off < 64; off <<= 1) {
        acc.x += __shfl_xor(acc.x, off, 64);
        acc.y += __shfl_xor(acc.y, off, 64);
        acc.z += __shfl_xor(acc.z, off, 64);
        acc.w += __shfl_xor(acc.w, off, 64);
    }
    if (eslot == 0) {
        float4 self = u4[(size_t)node * 4 + comp];
        float dv = dinv[node];
        float4 bb = ((const float4*)b)[comp];
        float4 r;
        r.x = fmaxf(fmaf(dv, acc.x + self.x, bb.x), 0.f);
        r.y = fmaxf(fmaf(dv, acc.y + self.y, bb.y), 0.f);
        r.z = fmaxf(fmaf(dv, acc.z + self.z, bb.z), 0.f);
        r.w = fmaxf(fmaf(dv, acc.w + self.w, bb.w), 0.f);
        ((float4*)hout)[(size_t)node * 4 + comp] = r;
    }
}

// ---------- final aggregate (3 dims) + bias + log_softmax ----------
__global__ void k_agg_out(const float4* __restrict__ u4p, const int* __restrict__ col,
                          const int* __restrict__ offs, const int* __restrict__ cnt,
                          const float* __restrict__ dinv, const float* __restrict__ b4,
                          float* __restrict__ out, int n) {
    int wave = threadIdx.x >> 6;
    int node = blockIdx.x * 4 + wave;
    if (node >= n) return;
    int lane = threadIdx.x & 63;
    int beg = offs[node], c = cnt[node];
    float a0 = 0.f, a1 = 0.f, a2 = 0.f;
    for (int i = lane; i < c; i += 64) {
        float4 v = u4p[col[beg + i]];
        a0 += v.x; a1 += v.y; a2 += v.z;
    }
    for (int off = 1; off < 64; off <<= 1) {
        a0 += __shfl_xor(a0, off, 64);
        a1 += __shfl_xor(a1, off, 64);
        a2 += __shfl_xor(a2, off, 64);
    }
    if (lane == 0) {
        float4 self = u4p[node];
        float dv = dinv[node];
        float v0 = fmaf(dv, a0 + self.x, b4[0]);
        float v1 = fmaf(dv, a1 + self.y, b4[1]);
        float v2 = fmaf(dv, a2 + self.z, b4[2]);
        float m = fmaxf(v0, fmaxf(v1, v2));
        float lse = m + logf(expf(v0 - m) + expf(v1 - m) + expf(v2 - m));
        out[(size_t)node * 3 + 0] = v0 - lse;
        out[(size_t)node * 3 + 1] = v1 - lse;
        out[(size_t)node * 3 + 2] = v2 - lse;
    }
}

extern "C" void kernel_launch(void* const* d_in, const int* in_sizes, int n_in,
                              void* d_out, int out_size, void* d_ws, size_t ws_size,
                              hipStream_t stream) {
    const float* x  = (const float*)d_in[0];
    const void*  ei = d_in[1];
    const float* W1 = (const float*)d_in[2];
    const float* b1 = (const float*)d_in[3];
    const float* W2 = (const float*)d_in[4];
    const float* b2 = (const float*)d_in[5];
    const float* W3 = (const float*)d_in[6];
    const float* b3 = (const float*)d_in[7];
    const float* W4 = (const float*)d_in[8];
    const float* b4 = (const float*)d_in[9];
    float* out = (float*)d_out;

    const int N = in_sizes[0] / 768;
    const int E = in_sizes[1] / 2;

    char* p = (char*)d_ws;
    auto alloc = [&](size_t bytes) {
        void* r = (void*)p;
        p += (bytes + 255) & ~(size_t)255;
        return r;
    };
    int*   cnt    = (int*)alloc((size_t)N * 4);
    int*   offs   = (int*)alloc((size_t)N * 4);
    int*   cursor = (int*)alloc((size_t)N * 4);
    int*   bsums  = (int*)alloc(4096);
    int*   flag   = (int*)alloc(256);
    float* dinv   = (float*)alloc((size_t)N * 4);
    int*   col    = (int*)alloc((size_t)E * 4);
    float* u      = (float*)alloc((size_t)N * 16 * 4);
    float* h      = (float*)alloc((size_t)N * 16 * 4);
    float4* u4p   = (float4*)alloc((size_t)N * 16);

    const int nbN = DIVUP(N, 256);
    const int nbE8 = DIVUP(E, 2048);  // 8 edges/thread
    const int nbT = DIVUP(4 * N, 256);
    const int nbA = DIVUP(N, 4);
    const int nbX = DIVUP(N, 64);     // transform768: 64 nodes/block

    k_detect<<<1, 64, 0, stream>>>(ei, flag);
    k_init<<<nbN, 256, 0, stream>>>(cnt, N);
    k_count<<<nbE8, 256, 0, stream>>>(ei, flag, cnt, E);
    k_scanA<<<nbN, 256, 0, stream>>>(cnt, offs, bsums, N);
    k_scanB<<<1, 512, 0, stream>>>(bsums, nbN);
    k_scanC<<<nbN, 256, 0, stream>>>(offs, cursor, bsums, cnt, dinv, N);
    k_fill<<<nbE8, 256, 0, stream>>>(ei, flag, cursor, col, E);

    // layer 1: transform(768->16) then aggregate
    k_transform768<<<nbX, 256, 0, stream>>>(x, W1, dinv, u, N);
    k_agg16<<<nbA, 256, 0, stream>>>(u, col, offs, cnt, dinv, b1, h, N);
    // layer 2
    k_transform16<<<nbT, 256, 0, stream>>>(h, W2, dinv, u, N);
    k_agg16<<<nbA, 256, 0, stream>>>(u, col, offs, cnt, dinv, b2, h, N);
    // layer 3
    k_transform16<<<nbT, 256, 0, stream>>>(h, W3, dinv, u, N);
    k_agg16<<<nbA, 256, 0, stream>>>(u, col, offs, cnt, dinv, b3, h, N);
    // layer 4: transform(16->3) then aggregate + log_softmax
    k_t4<<<nbN, 256, 0, stream>>>(h, W4, dinv, u4p, N);
    k_agg_out<<<nbA, 256, 0, stream>>>(u4p, col, offs, cnt, dinv, b4, out, N);
}

// Round 4
// 623.310 us; speedup vs baseline: 1.3736x; 1.1868x over previous
//
#include <hip/hip_runtime.h>
#include <hip/hip_bf16.h>

// GCN: 4 layers, D^{-1/2}(A+I)D^{-1/2} aggregation, log_softmax output.
// CSR built per call; u = dinv*(h@W) pre-scale, CSR gather sums, post-scale
// by dinv[dst], self-loop folded as +u[d]. Layer1/4 transform BEFORE agg.
// R1: k_fill/k_count latency-bound -> batched edges/thread.
// R2: transform768 LDS-staged x -> no effect (620 GB/s both ways).
// R3: real limiter = 768 global W-loads/lane (64B/instr, L1-thrash) + tiny
//     MLP + small grid. Fix: W1 in LDS, 4-way k-split (4x waves) + partial
//     reduce, agg16 4-deep MLP.

#define DIVUP(a, b) (((a) + (b) - 1) / (b))

// ---------- edge dtype detection (int64 vs int32 ABI ambiguity) ----------
__global__ void k_detect(const void* ei, int* flag) {
    int t = threadIdx.x;  // 64 threads
    const int* p = (const int*)ei;
    bool z = (p[2 * t + 1] == 0);
    unsigned long long m = __ballot(z);
    if (t == 0) *flag = (m == ~0ULL) ? 1 : 0;
}

__device__ __forceinline__ int load_idx(const void* ei, int is64, size_t pos) {
    if (is64) return (int)((const long long*)ei)[pos];
    return ((const int*)ei)[pos];
}

// ---------- degree count ----------
__global__ void k_init(int* cnt, int n) {
    int i = blockIdx.x * 256 + threadIdx.x;
    if (i < n) cnt[i] = 0;
}

__global__ void k_count(const void* ei, const int* flag, int* cnt, int E) {
    int base = blockIdx.x * 2048 + threadIdx.x;
    int is64 = *flag;
    int d[8];
    bool ok[8];
#pragma unroll
    for (int j = 0; j < 8; ++j) {
        int e = base + j * 256;
        ok[j] = (e < E);
        d[j] = ok[j] ? load_idx(ei, is64, (size_t)E + e) : 0;
    }
#pragma unroll
    for (int j = 0; j < 8; ++j)
        if (ok[j]) atomicAdd(&cnt[d[j]], 1);
}

// ---------- exclusive scan (3-phase) ----------
__global__ void k_scanA(const int* cnt, int* offs, int* bsums, int n) {
    __shared__ int s[256];
    int t = threadIdx.x;
    int i = blockIdx.x * 256 + t;
    int v = (i < n) ? cnt[i] : 0;
    s[t] = v;
    __syncthreads();
    for (int off = 1; off < 256; off <<= 1) {
        int add = (t >= off) ? s[t - off] : 0;
        __syncthreads();
        s[t] += add;
        __syncthreads();
    }
    if (i < n) offs[i] = s[t] - v;
    if (t == 255) bsums[blockIdx.x] = s[t];
}

__global__ void k_scanB(int* bsums, int nb) {
    __shared__ int s[512];
    int t = threadIdx.x;
    int v = (t < nb) ? bsums[t] : 0;
    s[t] = v;
    __syncthreads();
    for (int off = 1; off < 512; off <<= 1) {
        int add = (t >= off) ? s[t - off] : 0;
        __syncthreads();
        s[t] += add;
        __syncthreads();
    }
    if (t < nb) bsums[t] = s[t] - v;
}

__global__ void k_scanC(int* offs, int* cursor, const int* bsums,
                        const int* cnt, float* dinv, int n) {
    int i = blockIdx.x * 256 + threadIdx.x;
    if (i >= n) return;
    int o = offs[i] + bsums[blockIdx.x];
    offs[i] = o;
    cursor[i] = o;
    dinv[i] = rsqrtf((float)(cnt[i] + 1));  // +1 self-loop
}

// ---------- CSR fill: 8 edges/thread ----------
__global__ void k_fill(const void* ei, const int* flag, int* cursor, int* col, int E) {
    int base = blockIdx.x * 2048 + threadIdx.x;
    int is64 = *flag;
    int s[8], d[8], p[8];
    bool ok[8];
#pragma unroll
    for (int j = 0; j < 8; ++j) {
        int e = base + j * 256;
        ok[j] = (e < E);
        s[j] = ok[j] ? load_idx(ei, is64, (size_t)e) : 0;
        d[j] = ok[j] ? load_idx(ei, is64, (size_t)E + e) : 0;
    }
#pragma unroll
    for (int j = 0; j < 8; ++j)
        p[j] = ok[j] ? atomicAdd(&cursor[d[j]], 1) : 0;
#pragma unroll
    for (int j = 0; j < 8; ++j)
        if (ok[j]) col[p[j]] = s[j];
}

__device__ __forceinline__ void fma4(float s, const float4 w, float4& a) {
    a.x = fmaf(s, w.x, a.x);
    a.y = fmaf(s, w.y, a.y);
    a.z = fmaf(s, w.z, a.z);
    a.w = fmaf(s, w.w, a.w);
}

// ---------- layer-1 transform, k-split: part[s] = x[:, s*192:(s+1)*192] @ W1[slice] ----------
// Block = 256 threads = 4 waves; blockIdx encodes (nodeblock, slice).
// W1 slice (192x16) staged to LDS with padded row stride 20 floats
// (16B-aligned b128, wave-uniform k -> broadcast, conflict-free).
// x tiles staged per-wave (wave-private slice, no barrier in loop).
__global__ void k_transform768(const float* __restrict__ x, const float* __restrict__ W,
                               float* __restrict__ parts, int n) {
    __shared__ float Wl[192 * 20];      // 15360 B
    __shared__ float lx[4][16][68];     // 17408 B
    int slice = blockIdx.x & 3;
    int nblk = blockIdx.x >> 2;
    int tid = threadIdx.x;
    int wid = tid >> 6, lane = tid & 63;
    int nbase = nblk * 64 + wid * 16;
    int nloc = lane >> 2, og = lane & 3;
    int node = nbase + nloc;
    const float4* xg = (const float4*)x;
    const float4* wg = (const float4*)W;

    // stage W slice: 768 float4 (192 rows x 4), 3 per thread
#pragma unroll
    for (int i = tid; i < 768; i += 256) {
        float4 v = wg[slice * 768 + i];
        int k = i >> 2, g = i & 3;
        *(float4*)&Wl[k * 20 + g * 4] = v;
    }
    __syncthreads();

    float4 acc = {0.f, 0.f, 0.f, 0.f};
    const float* lxr = lx[wid][nloc];
#pragma unroll 1
    for (int t = 0; t < 3; ++t) {
        // stage 16 rows x 16 float4 of x (coalesced: 4 x 256B segments/instr)
#pragma unroll
        for (int r = 0; r < 4; ++r) {
            int f = r * 64 + lane;
            int srow = f >> 4, scol = f & 15;
            int nb = nbase + srow;
            if (nb < n) {
                float4 v = xg[(size_t)nb * 192 + slice * 48 + t * 16 + scol];
                *(float4*)&lx[wid][srow][scol * 4] = v;
            }
        }
#pragma unroll 4
        for (int kk = 0; kk < 16; ++kk) {
            float4 xv = *(const float4*)&lxr[kk * 4];
            int kb = (t * 16 + kk) * 4;  // k within slice
            fma4(xv.x, *(const float4*)&Wl[(kb + 0) * 20 + og * 4], acc);
            fma4(xv.y, *(const float4*)&Wl[(kb + 1) * 20 + og * 4], acc);
            fma4(xv.z, *(const float4*)&Wl[(kb + 2) * 20 + og * 4], acc);
            fma4(xv.w, *(const float4*)&Wl[(kb + 3) * 20 + og * 4], acc);
        }
    }
    if (node < n) {
        float4* dst = (float4*)(parts + (size_t)slice * n * 16);
        dst[(size_t)node * 4 + og] = acc;
    }
}

// ---------- reduce 4 partials, apply dinv: u = dinv * sum_s part[s] ----------
__global__ void k_red4(const float* __restrict__ parts, const float* __restrict__ dinv,
                       float* __restrict__ u, int n) {
    int g = blockIdx.x * 256 + threadIdx.x;  // float4 index over N*4
    if (g >= 4 * n) return;
    size_t stride = (size_t)n * 4;  // in float4
    const float4* p = (const float4*)parts;
    float4 a = p[g], b = p[g + stride], c = p[g + 2 * stride], d = p[g + 3 * stride];
    float s = dinv[g >> 2];
    float4 r;
    r.x = (a.x + b.x + c.x + d.x) * s;
    r.y = (a.y + b.y + c.y + d.y) * s;
    r.z = (a.z + b.z + c.z + d.z) * s;
    r.w = (a.w + b.w + c.w + d.w) * s;
    ((float4*)u)[g] = r;
}

// ---------- 16->16 transform: u = dinv * (h @ W) ----------
__global__ void k_transform16(const float* __restrict__ in, const float* __restrict__ W,
                              const float* __restrict__ dinv, float* __restrict__ out, int n) {
    int gid = blockIdx.x * 256 + threadIdx.x;
    int node = gid >> 2, og = gid & 3;
    if (node >= n) return;
    const float4* xr = (const float4*)(in + (size_t)node * 16);
    const float4* w4 = (const float4*)W;
    float4 acc = {0.f, 0.f, 0.f, 0.f};
#pragma unroll
    for (int kk = 0; kk < 4; ++kk) {
        float4 xv = xr[kk];
        int k4 = kk * 16;
        fma4(xv.x, w4[k4 + og], acc);
        fma4(xv.y, w4[k4 + 4 + og], acc);
        fma4(xv.z, w4[k4 + 8 + og], acc);
        fma4(xv.w, w4[k4 + 12 + og], acc);
    }
    float s = dinv[node];
    float4 r = {acc.x * s, acc.y * s, acc.z * s, acc.w * s};
    ((float4*)out)[(size_t)node * 4 + og] = r;
}

// ---------- layer-4 transform: u4 = dinv * (h @ W4), W4 (16,3) padded to float4 ----------
__global__ void k_t4(const float* __restrict__ h, const float* __restrict__ W4,
                     const float* __restrict__ dinv, float4* __restrict__ u4p, int n) {
    int node = blockIdx.x * 256 + threadIdx.x;
    if (node >= n) return;
    const float* hr = h + (size_t)node * 16;
    float a0 = 0.f, a1 = 0.f, a2 = 0.f;
#pragma unroll
    for (int k = 0; k < 16; ++k) {
        float hk = hr[k];
        a0 = fmaf(hk, W4[k * 3 + 0], a0);
        a1 = fmaf(hk, W4[k * 3 + 1], a1);
        a2 = fmaf(hk, W4[k * 3 + 2], a2);
    }
    float s = dinv[node];
    u4p[node] = make_float4(a0 * s, a1 * s, a2 * s, 0.f);
}

// ---------- aggregate 16-dim: h[d] = relu(dinv[d]*(sum_{src} u[src] + u[d]) + b) ----------
__global__ void k_agg16(const float* __restrict__ u, const int* __restrict__ col,
                        const int* __restrict__ offs, const int* __restrict__ cnt,
                        const float* __restrict__ dinv, const float* __restrict__ b,
                        float* __restrict__ hout, int n) {
    int wave = threadIdx.x >> 6;
    int node = blockIdx.x * 4 + wave;  // one wave per node
    if (node >= n) return;
    int lane = threadIdx.x & 63;
    int eslot = lane >> 2, comp = lane & 3;
    const float4* u4 = (const float4*)u;
    int beg = offs[node], c = cnt[node];
    float4 a0 = {0.f, 0.f, 0.f, 0.f}, a1 = a0, a2 = a0, a3 = a0;
    int i = eslot;
    for (; i + 48 < c; i += 64) {  // 4 independent gathers in flight
        int s0 = col[beg + i];
        int s1 = col[beg + i + 16];
        int s2 = col[beg + i + 32];
        int s3 = col[beg + i + 48];
        float4 v0 = u4[(size_t)s0 * 4 + comp];
        float4 v1 = u4[(size_t)s1 * 4 + comp];
        float4 v2 = u4[(size_t)s2 * 4 + comp];
        float4 v3 = u4[(size_t)s3 * 4 + comp];
        a0.x += v0.x; a0.y += v0.y; a0.z += v0.z; a0.w += v0.w;
        a1.x += v1.x; a1.y += v1.y; a1.z += v1.z; a1.w += v1.w;
        a2.x += v2.x; a2.y += v2.y; a2.z += v2.z; a2.w += v2.w;
        a3.x += v3.x; a3.y += v3.y; a3.z += v3.z; a3.w += v3.w;
    }
    for (; i < c; i += 16) {
        int s0 = col[beg + i];
        float4 v0 = u4[(size_t)s0 * 4 + comp];
        a0.x += v0.x; a0.y += v0.y; a0.z += v0.z; a0.w += v0.w;
    }
    a0.x += a1.x + a2.x + a3.x;
    a0.y += a1.y + a2.y + a3.y;
    a0.z += a1.z + a2.z + a3.z;
    a0.w += a1.w + a2.w + a3.w;
    for (int off = 4; off < 64; off <<= 1) {
        a0.x += __shfl_xor(a0.x, off, 64);
        a0.y += __shfl_xor(a0.y, off, 64);
        a0.z += __shfl_xor(a0.z, off, 64);
        a0.w += __shfl_xor(a0.w, off, 64);
    }
    if (eslot == 0) {
        float4 self = u4[(size_t)node * 4 + comp];
        float dv = dinv[node];
        float4 bb = ((const float4*)b)[comp];
        float4 r;
        r.x = fmaxf(fmaf(dv, a0.x + self.x, bb.x), 0.f);
        r.y = fmaxf(fmaf(dv, a0.y + self.y, bb.y), 0.f);
        r.z = fmaxf(fmaf(dv, a0.z + self.z, bb.z), 0.f);
        r.w = fmaxf(fmaf(dv, a0.w + self.w, bb.w), 0.f);
        ((float4*)hout)[(size_t)node * 4 + comp] = r;
    }
}

// ---------- final aggregate (3 dims) + bias + log_softmax ----------
__global__ void k_agg_out(const float4* __restrict__ u4p, const int* __restrict__ col,
                          const int* __restrict__ offs, const int* __restrict__ cnt,
                          const float* __restrict__ dinv, const float* __restrict__ b4,
                          float* __restrict__ out, int n) {
    int wave = threadIdx.x >> 6;
    int node = blockIdx.x * 4 + wave;
    if (node >= n) return;
    int lane = threadIdx.x & 63;
    int beg = offs[node], c = cnt[node];
    float a0 = 0.f, a1 = 0.f, a2 = 0.f;
    for (int i = lane; i < c; i += 64) {
        float4 v = u4p[col[beg + i]];
        a0 += v.x; a1 += v.y; a2 += v.z;
    }
    for (int off = 1; off < 64; off <<= 1) {
        a0 += __shfl_xor(a0, off, 64);
        a1 += __shfl_xor(a1, off, 64);
        a2 += __shfl_xor(a2, off, 64);
    }
    if (lane == 0) {
        float4 self = u4p[node];
        float dv = dinv[node];
        float v0 = fmaf(dv, a0 + self.x, b4[0]);
        float v1 = fmaf(dv, a1 + self.y, b4[1]);
        float v2 = fmaf(dv, a2 + self.z, b4[2]);
        float m = fmaxf(v0, fmaxf(v1, v2));
        float lse = m + logf(expf(v0 - m) + expf(v1 - m) + expf(v2 - m));
        out[(size_t)node * 3 + 0] = v0 - lse;
        out[(size_t)node * 3 + 1] = v1 - lse;
        out[(size_t)node * 3 + 2] = v2 - lse;
    }
}

extern "C" void kernel_launch(void* const* d_in, const int* in_sizes, int n_in,
                              void* d_out, int out_size, void* d_ws, size_t ws_size,
                              hipStream_t stream) {
    const float* x  = (const float*)d_in[0];
    const void*  ei = d_in[1];
    const float* W1 = (const float*)d_in[2];
    const float* b1 = (const float*)d_in[3];
    const float* W2 = (const float*)d_in[4];
    const float* b2 = (const float*)d_in[5];
    const float* W3 = (const float*)d_in[6];
    const float* b3 = (const float*)d_in[7];
    const float* W4 = (const float*)d_in[8];
    const float* b4 = (const float*)d_in[9];
    float* out = (float*)d_out;

    const int N = in_sizes[0] / 768;
    const int E = in_sizes[1] / 2;

    char* p = (char*)d_ws;
    auto alloc = [&](size_t bytes) {
        void* r = (void*)p;
        p += (bytes + 255) & ~(size_t)255;
        return r;
    };
    int*   cnt    = (int*)alloc((size_t)N * 4);
    int*   offs   = (int*)alloc((size_t)N * 4);
    int*   cursor = (int*)alloc((size_t)N * 4);
    int*   bsums  = (int*)alloc(4096);
    int*   flag   = (int*)alloc(256);
    float* dinv   = (float*)alloc((size_t)N * 4);
    int*   col    = (int*)alloc((size_t)E * 4);
    float* u      = (float*)alloc((size_t)N * 16 * 4);
    float* h      = (float*)alloc((size_t)N * 16 * 4);
    float4* u4p   = (float4*)alloc((size_t)N * 16);
    float* parts  = (float*)alloc((size_t)4 * N * 16 * 4);  // 25.6 MB

    const int nbN = DIVUP(N, 256);
    const int nbE8 = DIVUP(E, 2048);
    const int nbT = DIVUP(4 * N, 256);
    const int nbA = DIVUP(N, 4);
    const int nbX = DIVUP(N, 64) * 4;  // (nodeblock, slice)

    k_detect<<<1, 64, 0, stream>>>(ei, flag);
    k_init<<<nbN, 256, 0, stream>>>(cnt, N);
    k_count<<<nbE8, 256, 0, stream>>>(ei, flag, cnt, E);
    k_scanA<<<nbN, 256, 0, stream>>>(cnt, offs, bsums, N);
    k_scanB<<<1, 512, 0, stream>>>(bsums, nbN);
    k_scanC<<<nbN, 256, 0, stream>>>(offs, cursor, bsums, cnt, dinv, N);
    k_fill<<<nbE8, 256, 0, stream>>>(ei, flag, cursor, col, E);

    // layer 1: transform(768->16) via 4-way k-split, then reduce, then aggregate
    k_transform768<<<nbX, 256, 0, stream>>>(x, W1, parts, N);
    k_red4<<<nbT, 256, 0, stream>>>(parts, dinv, u, N);
    k_agg16<<<nbA, 256, 0, stream>>>(u, col, offs, cnt, dinv, b1, h, N);
    // layer 2
    k_transform16<<<nbT, 256, 0, stream>>>(h, W2, dinv, u, N);
    k_agg16<<<nbA, 256, 0, stream>>>(u, col, offs, cnt, dinv, b2, h, N);
    // layer 3
    k_transform16<<<nbT, 256, 0, stream>>>(h, W3, dinv, u, N);
    k_agg16<<<nbA, 256, 0, stream>>>(u, col, offs, cnt, dinv, b3, h, N);
    // layer 4: transform(16->3) then aggregate + log_softmax
    k_t4<<<nbN, 256, 0, stream>>>(h, W4, dinv, u4p, N);
    k_agg_out<<<nbA, 256, 0, stream>>>(u4p, col, offs, cnt, dinv, b4, out, N);
}